// Round 1
// baseline (18.659 us; speedup 1.0000x reference)
//
#include <hip/hip_runtime.h>

#define NHID 8

__global__ __launch_bounds__(256) void P1_mlp_kernel(
    const float* __restrict__ x,
    const float* __restrict__ w_in, const float* __restrict__ b_in,
    const float* __restrict__ w_hid, const float* __restrict__ b_hid,
    const float* __restrict__ w_out, const float* __restrict__ b_out,
    float* __restrict__ out, int n)
{
    // Weights: uniform global loads -> scalar regs (addresses are thread-invariant).
    const float wi0 = w_in[0], wi1 = w_in[1];
    const float bi0 = b_in[0], bi1 = b_in[1];
    float wh[NHID][4];
    float bh[NHID][2];
#pragma unroll
    for (int l = 0; l < NHID; ++l) {
        wh[l][0] = w_hid[l * 4 + 0];  // W[l][0][0]
        wh[l][1] = w_hid[l * 4 + 1];  // W[l][0][1]
        wh[l][2] = w_hid[l * 4 + 2];  // W[l][1][0]
        wh[l][3] = w_hid[l * 4 + 3];  // W[l][1][1]
        bh[l][0] = b_hid[l * 2 + 0];
        bh[l][1] = b_hid[l * 2 + 1];
    }
    const float wo0 = w_out[0], wo1 = w_out[1], bo = b_out[0];

    const int tid = blockIdx.x * blockDim.x + threadIdx.x;
    const int stride = gridDim.x * blockDim.x;
    const int nv = n >> 2;  // float4 count

    const float4* __restrict__ x4 = (const float4*)x;
    float4* __restrict__ o4 = (float4*)out;

    for (int i = tid; i < nv; i += stride) {
        const float4 xv = x4[i];
        float xin[4] = {xv.x, xv.y, xv.z, xv.w};
        float r[4];
#pragma unroll
        for (int e = 0; e < 4; ++e) {
            float h0 = fmaxf(fmaf(xin[e], wi0, bi0), 0.0f);
            float h1 = fmaxf(fmaf(xin[e], wi1, bi1), 0.0f);
#pragma unroll
            for (int l = 0; l < NHID; ++l) {
                float n0 = fmaxf(fmaf(h1, wh[l][1], fmaf(h0, wh[l][0], bh[l][0])), 0.0f);
                float n1 = fmaxf(fmaf(h1, wh[l][3], fmaf(h0, wh[l][2], bh[l][1])), 0.0f);
                h0 = n0;
                h1 = n1;
            }
            r[e] = fmaxf(fmaf(h1, wo1, fmaf(h0, wo0, bo)), 0.0f);
        }
        float4 ov;
        ov.x = r[0]; ov.y = r[1]; ov.z = r[2]; ov.w = r[3];
        o4[i] = ov;
    }

    // Scalar tail (N=8M is divisible by 4, but stay robust).
    const int tail_base = nv << 2;
    const int tail_n = n - tail_base;
    if (tid < tail_n) {
        const float xx = x[tail_base + tid];
        float h0 = fmaxf(fmaf(xx, wi0, bi0), 0.0f);
        float h1 = fmaxf(fmaf(xx, wi1, bi1), 0.0f);
#pragma unroll
        for (int l = 0; l < NHID; ++l) {
            float n0 = fmaxf(fmaf(h1, wh[l][1], fmaf(h0, wh[l][0], bh[l][0])), 0.0f);
            float n1 = fmaxf(fmaf(h1, wh[l][3], fmaf(h0, wh[l][2], bh[l][1])), 0.0f);
            h0 = n0;
            h1 = n1;
        }
        out[tail_base + tid] = fmaxf(fmaf(h1, wo1, fmaf(h0, wo0, bo)), 0.0f);
    }
}

extern "C" void kernel_launch(void* const* d_in, const int* in_sizes, int n_in,
                              void* d_out, int out_size, void* d_ws, size_t ws_size,
                              hipStream_t stream) {
    const float* x     = (const float*)d_in[0];
    const float* w_in  = (const float*)d_in[1];
    const float* b_in  = (const float*)d_in[2];
    const float* w_hid = (const float*)d_in[3];
    const float* b_hid = (const float*)d_in[4];
    const float* w_out = (const float*)d_in[5];
    const float* b_out = (const float*)d_in[6];
    float* out = (float*)d_out;

    const int n = in_sizes[0];  // 8,000,000
    const int nv = (n + 3) / 4;
    const int block = 256;
    int grid = (nv + block - 1) / block;
    if (grid > 2048) grid = 2048;

    P1_mlp_kernel<<<grid, block, 0, stream>>>(x, w_in, b_in, w_hid, b_hid,
                                              w_out, b_out, out, n);
}